// Round 3
// baseline (2228.623 us; speedup 1.0000x reference)
//
#include <hip/hip_runtime.h>
#include <hip/hip_bf16.h>

#define NSPEC 7
#define B_ 64
#define A_ 32
#define NATOM 2048
#define DIN 1008

#define PI_F 3.14159265358979323846f

__device__ __forceinline__ float celu01(float x) {
    return x > 0.f ? x : 0.1f * expm1f(x * 10.f);
}

// ---------------- init: zero species counts, energy[b] = sum_a sae[species] --
__global__ __launch_bounds__(64) void init_kernel(const int* __restrict__ species,
                                                  const float* __restrict__ sae,
                                                  float* __restrict__ energy,
                                                  int* __restrict__ counts) {
    int t = threadIdx.x;
    if (t < NSPEC) counts[t] = 0;
    float ssum = 0.f;
    for (int j = 0; j < A_; ++j) ssum += sae[species[t * A_ + j]];
    energy[t] = ssum;
}

// ---------------- bucket atoms by species ----------------------------------
__global__ __launch_bounds__(256) void bucket_kernel(const int* __restrict__ species,
                                                     int* __restrict__ counts,
                                                     int* __restrict__ lists) {
    int a = blockIdx.x * 256 + threadIdx.x;
    if (a < NATOM) {
        int s = species[a];
        int p = atomicAdd(&counts[s], 1);
        lists[s * NATOM + p] = a;
    }
}

// ---------------- AEV: one block per (b,i) ---------------------------------
__global__ __launch_bounds__(256) void aev_kernel(const int* __restrict__ species,
                                                  const float* __restrict__ coords,
                                                  float* __restrict__ aev) {
    const int bi = blockIdx.x;
    const int b = bi >> 5, i = bi & 31;
    const int tid = threadIdx.x;

    __shared__ float ux[32], uy[32], uz[32], dst[32], fcr[32], fca[32];
    __shared__ int spc[32];
    __shared__ float cs_[496], sn_[496], ad_[496], w_[496];
    __shared__ int bk_[496];
    __shared__ int npairs;
    __shared__ float ang[896];
    __shared__ float rad[112];

    if (tid == 0) npairs = 0;
    for (int x = tid; x < 896; x += 256) ang[x] = 0.f;
    if (tid < 112) rad[tid] = 0.f;
    if (tid < 32) {
        int j = tid;
        float dx = coords[(b * A_ + j) * 3 + 0] - coords[(b * A_ + i) * 3 + 0];
        float dy = coords[(b * A_ + j) * 3 + 1] - coords[(b * A_ + i) * 3 + 1];
        float dz = coords[(b * A_ + j) * 3 + 2] - coords[(b * A_ + i) * 3 + 2];
        float d = sqrtf(dx * dx + dy * dy + dz * dz + 1e-12f);
        float inv = 1.f / d;
        ux[j] = dx * inv; uy[j] = dy * inv; uz[j] = dz * inv;
        dst[j] = d;
        fcr[j] = (j != i && d < 5.1f) ? 0.5f * cosf(PI_F * d / 5.1f) + 0.5f : 0.f;
        fca[j] = (j != i && d < 3.5f) ? 0.5f * cosf(PI_F * d / 3.5f) + 0.5f : 0.f;
        spc[j] = species[b * A_ + j];
    }
    __syncthreads();

    // pair build (j<k), compact surviving pairs
    for (int p = tid; p < 496; p += 256) {
        int j = (int)floorf((63.0f - sqrtf(3969.0f - 8.0f * (float)p)) * 0.5f);
        while ((j + 1) * (63 - (j + 1)) / 2 <= p) ++j;
        while (j * (63 - j) / 2 > p) --j;
        int k = p - j * (63 - j) / 2 + j + 1;
        float w = fca[j] * fca[k];
        if (w > 0.f) {
            float ct = ux[j] * ux[k] + uy[j] * uy[k] + uz[j] * uz[k];
            ct = fminf(1.f, fmaxf(-1.f, ct));
            float cs = 0.95f * ct;
            float sn = sqrtf(1.f - cs * cs);
            int idx = atomicAdd(&npairs, 1);
            cs_[idx] = cs;
            sn_[idx] = sn;
            ad_[idx] = 0.5f * (dst[j] + dst[k]);
            w_[idx] = 2.f * w;  // fold the unordered->ordered factor 2
            int sj = spc[j], sk = spc[k];
            int lo = min(sj, sk), hi = max(sj, sk);
            bk_[idx] = lo * 7 - lo * (lo - 1) / 2 + (hi - lo);
        }
    }
    // radial (threads 0..15, one shift each)
    if (tid < 16) {
        float shf = 0.8f + 0.26875f * (float)tid;
        for (int j = 0; j < 32; ++j) {
            if (fcr[j] > 0.f) {
                float dd = dst[j] - shf;
                float v = 0.25f * expf(-19.7f * dd * dd) * fcr[j];
                atomicAdd(&rad[spc[j] * 16 + tid], v);
            }
        }
    }
    __syncthreads();

    const float CZ[4] = {0.92387953f, 0.38268343f, -0.38268343f, -0.92387953f};
    const float SZ[4] = {0.38268343f, 0.92387953f, 0.92387953f, 0.38268343f};
    const int np = npairs;
    const int t = tid & 31, z = t >> 3, aa = t & 7;
    const float cz = CZ[z], sz = SZ[z];
    const float shfa = 0.8f + 0.3375f * (float)aa;
    for (int pr = tid >> 5; pr < np; pr += 8) {
        float f1b = 0.5f * (1.f + cs_[pr] * cz + sn_[pr] * sz);
        float f1 = exp2f(14.1f * log2f(fmaxf(f1b, 1e-30f)));
        float d2 = ad_[pr] - shfa;
        float f2 = expf(-12.5f * d2 * d2);
        atomicAdd(&ang[bk_[pr] * 32 + t], w_[pr] * f1 * f2);
    }
    __syncthreads();
    float* out = aev + (size_t)(b * A_ + i) * DIN;
    for (int x = tid; x < 112; x += 256) out[x] = rad[x];
    for (int x = tid; x < 896; x += 256) out[112 + x] = ang[x];
}

// ---------------- fused MLP: one block per (e, s, 64-atom chunk) -----------
__global__ __launch_bounds__(256) void mlp_kernel(
    const float* __restrict__ aev,
    const float* __restrict__ W0, const float* __restrict__ b0,
    const float* __restrict__ W1, const float* __restrict__ b1,
    const float* __restrict__ W2, const float* __restrict__ b2,
    const float* __restrict__ W3, const float* __restrict__ b3,
    const int* __restrict__ counts, const int* __restrict__ lists,
    float* __restrict__ energy) {

    const int chunk = blockIdx.x, s = blockIdx.y, e = blockIdx.z;
    const int n = counts[s];
    const int a0 = chunk * 64;
    if (a0 >= n) return;
    const int tid = threadIdx.x;
    const int es = e * NSPEC + s;

    __shared__ float xs[16][68];
    __shared__ float hb[256 * 68];  // h0, later reused for h2
    __shared__ float h1[192 * 68];
    __shared__ int atoms[64];

    if (tid < 64) atoms[tid] = (a0 + tid < n) ? lists[s * NATOM + a0 + tid] : -1;
    __syncthreads();

    // ---- layer 0: 1008 -> 256
    {
        const float* W0p = W0 + (size_t)es * DIN * 256;
        const int c0 = (tid & 63) * 4;
        const int ar = (tid >> 6) * 16;
        float acc[4][16];
        #pragma unroll
        for (int cc = 0; cc < 4; ++cc)
            #pragma unroll
            for (int r = 0; r < 16; ++r) acc[cc][r] = 0.f;

        const int la = tid >> 2, ld0 = (tid & 3) * 4;
        const int lat = atoms[la];

        for (int k0 = 0; k0 < DIN; k0 += 16) {
            float4 xv = make_float4(0.f, 0.f, 0.f, 0.f);
            if (lat >= 0) xv = *(const float4*)(aev + (size_t)lat * DIN + k0 + ld0);
            __syncthreads();
            xs[ld0 + 0][la] = xv.x;
            xs[ld0 + 1][la] = xv.y;
            xs[ld0 + 2][la] = xv.z;
            xs[ld0 + 3][la] = xv.w;
            __syncthreads();
            #pragma unroll
            for (int dd = 0; dd < 16; ++dd) {
                const float4 wv = *(const float4*)(W0p + (size_t)(k0 + dd) * 256 + c0);
                const float wc[4] = {wv.x, wv.y, wv.z, wv.w};
                #pragma unroll
                for (int q = 0; q < 4; ++q) {
                    const float4 x4 = *(const float4*)&xs[dd][ar + q * 4];
                    const float xr[4] = {x4.x, x4.y, x4.z, x4.w};
                    #pragma unroll
                    for (int cc = 0; cc < 4; ++cc)
                        #pragma unroll
                        for (int r = 0; r < 4; ++r)
                            acc[cc][q * 4 + r] += wc[cc] * xr[r];
                }
            }
        }
        const float4 bv = *(const float4*)(b0 + (size_t)es * 256 + c0);
        const float bc[4] = {bv.x, bv.y, bv.z, bv.w};
        #pragma unroll
        for (int cc = 0; cc < 4; ++cc)
            #pragma unroll
            for (int r = 0; r < 16; ++r)
                hb[(c0 + cc) * 68 + ar + r] = celu01(acc[cc][r] + bc[cc]);
    }
    __syncthreads();

    // ---- layer 1: 256 -> 192
    {
        const float* W1p = W1 + (size_t)es * 256 * 192;
        if (tid < 192) {
            const int c0 = (tid % 48) * 4;
            const int ar = (tid / 48) * 16;
            float acc[4][16];
            #pragma unroll
            for (int cc = 0; cc < 4; ++cc)
                #pragma unroll
                for (int r = 0; r < 16; ++r) acc[cc][r] = 0.f;
            for (int k = 0; k < 256; ++k) {
                const float4 wv = *(const float4*)(W1p + (size_t)k * 192 + c0);
                const float wc[4] = {wv.x, wv.y, wv.z, wv.w};
                #pragma unroll
                for (int q = 0; q < 4; ++q) {
                    const float4 x4 = *(const float4*)&hb[k * 68 + ar + q * 4];
                    const float xr[4] = {x4.x, x4.y, x4.z, x4.w};
                    #pragma unroll
                    for (int cc = 0; cc < 4; ++cc)
                        #pragma unroll
                        for (int r = 0; r < 4; ++r)
                            acc[cc][q * 4 + r] += wc[cc] * xr[r];
                }
            }
            const float4 bv = *(const float4*)(b1 + (size_t)es * 192 + c0);
            const float bc[4] = {bv.x, bv.y, bv.z, bv.w};
            #pragma unroll
            for (int cc = 0; cc < 4; ++cc)
                #pragma unroll
                for (int r = 0; r < 16; ++r)
                    h1[(c0 + cc) * 68 + ar + r] = celu01(acc[cc][r] + bc[cc]);
        }
    }
    __syncthreads();

    // ---- layer 2: 192 -> 160  (output into hb region)
    {
        const float* W2p = W2 + (size_t)es * 192 * 160;
        if (tid < 160) {
            const int c0 = (tid % 40) * 4;
            const int ar = (tid / 40) * 16;
            float acc[4][16];
            #pragma unroll
            for (int cc = 0; cc < 4; ++cc)
                #pragma unroll
                for (int r = 0; r < 16; ++r) acc[cc][r] = 0.f;
            for (int k = 0; k < 192; ++k) {
                const float4 wv = *(const float4*)(W2p + (size_t)k * 160 + c0);
                const float wc[4] = {wv.x, wv.y, wv.z, wv.w};
                #pragma unroll
                for (int q = 0; q < 4; ++q) {
                    const float4 x4 = *(const float4*)&h1[k * 68 + ar + q * 4];
                    const float xr[4] = {x4.x, x4.y, x4.z, x4.w};
                    #pragma unroll
                    for (int cc = 0; cc < 4; ++cc)
                        #pragma unroll
                        for (int r = 0; r < 4; ++r)
                            acc[cc][q * 4 + r] += wc[cc] * xr[r];
                }
            }
            const float4 bv = *(const float4*)(b2 + (size_t)es * 160 + c0);
            const float bc[4] = {bv.x, bv.y, bv.z, bv.w};
            #pragma unroll
            for (int cc = 0; cc < 4; ++cc)
                #pragma unroll
                for (int r = 0; r < 16; ++r)
                    hb[(c0 + cc) * 68 + ar + r] = celu01(acc[cc][r] + bc[cc]);
        }
    }
    __syncthreads();

    // ---- layer 3: 160 -> 1, accumulate into energies
    if (tid < 64) {
        const float* W3p = W3 + (size_t)es * 160;
        float acc = b3[es];
        for (int k = 0; k < 160; ++k) acc += hb[k * 68 + tid] * W3p[k];
        const int at = atoms[tid];
        if (at >= 0) atomicAdd(&energy[at >> 5], acc * 0.125f);
    }
}

extern "C" void kernel_launch(void* const* d_in, const int* in_sizes, int n_in,
                              void* d_out, int out_size, void* d_ws, size_t ws_size,
                              hipStream_t stream) {
    (void)in_sizes; (void)n_in; (void)out_size; (void)ws_size;
    const int* species = (const int*)d_in[0];
    const float* coords = (const float*)d_in[1];
    const float* W0 = (const float*)d_in[2];
    const float* b0 = (const float*)d_in[3];
    const float* W1 = (const float*)d_in[4];
    const float* b1 = (const float*)d_in[5];
    const float* W2 = (const float*)d_in[6];
    const float* b2 = (const float*)d_in[7];
    const float* W3 = (const float*)d_in[8];
    const float* b3 = (const float*)d_in[9];
    const float* sae = (const float*)d_in[10];
    float* energy = (float*)d_out;

    float* aev = (float*)d_ws;
    size_t off = (size_t)NATOM * DIN * sizeof(float);
    int* counts = (int*)((char*)d_ws + off);
    int* lists = (int*)((char*)d_ws + off + 64);

    hipLaunchKernelGGL(init_kernel, dim3(1), dim3(64), 0, stream,
                       species, sae, energy, counts);
    hipLaunchKernelGGL(bucket_kernel, dim3(8), dim3(256), 0, stream,
                       species, counts, lists);
    hipLaunchKernelGGL(aev_kernel, dim3(NATOM), dim3(256), 0, stream,
                       species, coords, aev);
    hipLaunchKernelGGL(mlp_kernel, dim3(32, NSPEC, 8), dim3(256), 0, stream,
                       aev, W0, b0, W1, b1, W2, b2, W3, b3, counts, lists, energy);
}

// Round 5
// 627.140 us; speedup vs baseline: 3.5536x; 3.5536x over previous
//
#include <hip/hip_runtime.h>
#include <hip/hip_bf16.h>

#define NSPEC 7
#define NATOM 2048
#define DIN 1008
#define MAXROWS 2496   // sum of per-species 64-padded counts <= 2048 + 7*63

#define PI_F 3.14159265358979323846f

__device__ __forceinline__ float celu01(float x) {
    return x > 0.f ? x : 0.1f * expm1f(x * 10.f);
}

// ---------------- init: zero counts, energy[b] = sum_a sae[species] --------
__global__ __launch_bounds__(64) void init_kernel(const int* __restrict__ species,
                                                  const float* __restrict__ sae,
                                                  float* __restrict__ energy,
                                                  int* __restrict__ counts) {
    int t = threadIdx.x;
    if (t < NSPEC) counts[t] = 0;
    float ssum = 0.f;
    for (int j = 0; j < 32; ++j) ssum += sae[species[t * 32 + j]];
    energy[t] = ssum;
}

// ---------------- bucket atoms by species ----------------------------------
__global__ __launch_bounds__(256) void bucket_kernel(const int* __restrict__ species,
                                                     int* __restrict__ counts,
                                                     int* __restrict__ lists) {
    int a = blockIdx.x * 256 + threadIdx.x;
    if (a < NATOM) {
        int s = species[a];
        int p = atomicAdd(&counts[s], 1);
        lists[s * NATOM + p] = a;
    }
}

// ---------------- prefix bases (64-padded) + rowmap ------------------------
__global__ __launch_bounds__(256) void prep_kernel(const int* __restrict__ counts,
                                                   const int* __restrict__ lists,
                                                   int* __restrict__ bases,
                                                   int* __restrict__ rowmap) {
    int t = threadIdx.x;
    int sb = 0;
    for (int s = 0; s < NSPEC; ++s) {
        int n = counts[s];
        int padc = (n + 63) & ~63;
        if (t == 0) bases[s] = sb;
        for (int p = t; p < padc; p += 256)
            rowmap[sb + p] = (p < n) ? lists[s * NATOM + p] : -1;
        sb += padc;
    }
    if (t == 0) bases[7] = sb;
}

// ---------------- AEV: one block per (b,i) ---------------------------------
__global__ __launch_bounds__(256) void aev_kernel(const int* __restrict__ species,
                                                  const float* __restrict__ coords,
                                                  float* __restrict__ aev) {
    const int bi = blockIdx.x;
    const int b = bi >> 5, i = bi & 31;
    const int tid = threadIdx.x;

    __shared__ float ux[32], uy[32], uz[32], dst[32], fcr[32], fca[32];
    __shared__ int spc[32];
    __shared__ float cs_[496], sn_[496], ad_[496], w_[496];
    __shared__ int bk_[496];
    __shared__ int npairs;
    __shared__ float ang[896];
    __shared__ float rad[112];

    if (tid == 0) npairs = 0;
    for (int x = tid; x < 896; x += 256) ang[x] = 0.f;
    if (tid < 112) rad[tid] = 0.f;
    if (tid < 32) {
        int j = tid;
        float dx = coords[(b * 32 + j) * 3 + 0] - coords[(b * 32 + i) * 3 + 0];
        float dy = coords[(b * 32 + j) * 3 + 1] - coords[(b * 32 + i) * 3 + 1];
        float dz = coords[(b * 32 + j) * 3 + 2] - coords[(b * 32 + i) * 3 + 2];
        float d = sqrtf(dx * dx + dy * dy + dz * dz + 1e-12f);
        float inv = 1.f / d;
        ux[j] = dx * inv; uy[j] = dy * inv; uz[j] = dz * inv;
        dst[j] = d;
        fcr[j] = (j != i && d < 5.1f) ? 0.5f * cosf(PI_F * d / 5.1f) + 0.5f : 0.f;
        fca[j] = (j != i && d < 3.5f) ? 0.5f * cosf(PI_F * d / 3.5f) + 0.5f : 0.f;
        spc[j] = species[b * 32 + j];
    }
    __syncthreads();

    for (int p = tid; p < 496; p += 256) {
        int j = (int)floorf((63.0f - sqrtf(3969.0f - 8.0f * (float)p)) * 0.5f);
        while ((j + 1) * (63 - (j + 1)) / 2 <= p) ++j;
        while (j * (63 - j) / 2 > p) --j;
        int k = p - j * (63 - j) / 2 + j + 1;
        float w = fca[j] * fca[k];
        if (w > 0.f) {
            float ct = ux[j] * ux[k] + uy[j] * uy[k] + uz[j] * uz[k];
            ct = fminf(1.f, fmaxf(-1.f, ct));
            float cs = 0.95f * ct;
            float sn = sqrtf(1.f - cs * cs);
            int idx = atomicAdd(&npairs, 1);
            cs_[idx] = cs;
            sn_[idx] = sn;
            ad_[idx] = 0.5f * (dst[j] + dst[k]);
            w_[idx] = 2.f * w;
            int sj = spc[j], sk = spc[k];
            int lo = min(sj, sk), hi = max(sj, sk);
            bk_[idx] = lo * 7 - lo * (lo - 1) / 2 + (hi - lo);
        }
    }
    if (tid < 16) {
        float shf = 0.8f + 0.26875f * (float)tid;
        for (int j = 0; j < 32; ++j) {
            if (fcr[j] > 0.f) {
                float dd = dst[j] - shf;
                float v = 0.25f * expf(-19.7f * dd * dd) * fcr[j];
                atomicAdd(&rad[spc[j] * 16 + tid], v);
            }
        }
    }
    __syncthreads();

    const float CZ[4] = {0.92387953f, 0.38268343f, -0.38268343f, -0.92387953f};
    const float SZ[4] = {0.38268343f, 0.92387953f, 0.92387953f, 0.38268343f};
    const int np = npairs;
    const int t = tid & 31, z = t >> 3, aa = t & 7;
    const float cz = CZ[z], sz = SZ[z];
    const float shfa = 0.8f + 0.3375f * (float)aa;
    for (int pr = tid >> 5; pr < np; pr += 8) {
        float f1b = 0.5f * (1.f + cs_[pr] * cz + sn_[pr] * sz);
        float f1 = exp2f(14.1f * log2f(fmaxf(f1b, 1e-30f)));
        float d2 = ad_[pr] - shfa;
        float f2 = expf(-12.5f * d2 * d2);
        atomicAdd(&ang[bk_[pr] * 32 + t], w_[pr] * f1 * f2);
    }
    __syncthreads();
    float* out = aev + (size_t)(b * 32 + i) * DIN;
    for (int x = tid; x < 112; x += 256) out[x] = rad[x];
    for (int x = tid; x < 896; x += 256) out[112 + x] = ang[x];
}

// ---------------- generic per-(e,s) GEMM: Y = celu(X @ W + b) --------------
// If rowgather != nullptr: X row r is aev[rowgather[base+r]] (|-1 -> zeros),
// else X row r is X[(base+r)*ldx + xeb*e].
// W[es][K][Ne], b[es][Ne], Y[(base+r)*ldy + e*Ne + c].
// grid: (colchunk, rowchunk, es), block 256, tile 64x64, BK=16, double-buffered.
__global__ __launch_bounds__(256) void gemm_es(
    const float* __restrict__ X, int ldx, int xeb,
    const int* __restrict__ rowgather,
    const float* __restrict__ W, const float* __restrict__ Bv,
    float* __restrict__ Y, int ldy,
    int K, int Ne, int NT,
    const int* __restrict__ bases, const int* __restrict__ counts) {

    const int es = blockIdx.z;
    const int e = es / NSPEC, s = es % NSPEC;
    const int n = counts[s];
    const int rows0 = blockIdx.y * 64;
    if (rows0 >= n) return;
    const int base = bases[s];
    const int col0 = blockIdx.x * 64;

    const int tid = threadIdx.x;
    const int tx = tid & 15, ty = tid >> 4;     // 16x16 threads, 4x4 outputs each
    const int ty4 = ty * 4, tx4 = tx * 4;

    __shared__ float Xt[2][64][20];  // [row][k], padded stride 20
    __shared__ float Wt[2][16][64];  // [k][col]

    const int lr = tid >> 2, lkq = (tid & 3) * 4;        // X: row, k-quad
    const int wkk = tid >> 4, wcf = tid & 15;            // W: k, col-quad

    const float* Xbase;
    bool xvalid = true;
    if (rowgather) {
        int atom = rowgather[base + rows0 + lr];
        xvalid = atom >= 0;
        Xbase = X + (size_t)(xvalid ? atom : 0) * ldx;
    } else {
        Xbase = X + (size_t)(base + rows0 + lr) * ldx + (size_t)xeb * e;
    }
    const float* Wbase = W + ((size_t)es * K) * Ne;

    float acc[4][4];
    #pragma unroll
    for (int i = 0; i < 4; ++i)
        #pragma unroll
        for (int j = 0; j < 4; ++j) acc[i][j] = 0.f;

    float4 xv = xvalid ? *(const float4*)(Xbase + lkq) : make_float4(0.f, 0.f, 0.f, 0.f);
    float4 wv;
    {
        int c = col0 + wcf * 4;
        if (c + 3 < Ne) wv = *(const float4*)(Wbase + (size_t)wkk * Ne + c);
        else {
            wv.x = Wbase[(size_t)wkk * Ne + min(c + 0, Ne - 1)];
            wv.y = Wbase[(size_t)wkk * Ne + min(c + 1, Ne - 1)];
            wv.z = Wbase[(size_t)wkk * Ne + min(c + 2, Ne - 1)];
            wv.w = Wbase[(size_t)wkk * Ne + min(c + 3, Ne - 1)];
        }
    }
    *(float4*)&Xt[0][lr][lkq] = xv;
    *(float4*)&Wt[0][wkk][wcf * 4] = wv;
    __syncthreads();

    for (int t = 0; t < NT; ++t) {
        const int cur = t & 1, nxt = cur ^ 1;
        if (t + 1 < NT) {
            int k0 = (t + 1) * 16;
            xv = xvalid ? *(const float4*)(Xbase + k0 + lkq) : make_float4(0.f, 0.f, 0.f, 0.f);
            int c = col0 + wcf * 4;
            if (c + 3 < Ne) wv = *(const float4*)(Wbase + (size_t)(k0 + wkk) * Ne + c);
            else {
                wv.x = Wbase[(size_t)(k0 + wkk) * Ne + min(c + 0, Ne - 1)];
                wv.y = Wbase[(size_t)(k0 + wkk) * Ne + min(c + 1, Ne - 1)];
                wv.z = Wbase[(size_t)(k0 + wkk) * Ne + min(c + 2, Ne - 1)];
                wv.w = Wbase[(size_t)(k0 + wkk) * Ne + min(c + 3, Ne - 1)];
            }
        }
        #pragma unroll
        for (int kq = 0; kq < 4; ++kq) {
            float4 x4[4];
            #pragma unroll
            for (int i = 0; i < 4; ++i)
                x4[i] = *(const float4*)&Xt[cur][ty4 + i][kq * 4];
            #pragma unroll
            for (int m = 0; m < 4; ++m) {
                float4 w4 = *(const float4*)&Wt[cur][kq * 4 + m][tx4];
                const float wj[4] = {w4.x, w4.y, w4.z, w4.w};
                #pragma unroll
                for (int i = 0; i < 4; ++i) {
                    float xm = (&x4[i].x)[m];
                    #pragma unroll
                    for (int j = 0; j < 4; ++j)
                        acc[i][j] += xm * wj[j];
                }
            }
        }
        if (t + 1 < NT) {
            __syncthreads();
            *(float4*)&Xt[nxt][lr][lkq] = xv;
            *(float4*)&Wt[nxt][wkk][wcf * 4] = wv;
            __syncthreads();
        }
    }

    const int c = col0 + tx4;
    float bc[4];
    #pragma unroll
    for (int j = 0; j < 4; ++j)
        bc[j] = Bv[(size_t)es * Ne + min(c + j, Ne - 1)];
    #pragma unroll
    for (int i = 0; i < 4; ++i) {
        size_t yoff = (size_t)(base + rows0 + ty4 + i) * ldy + (size_t)e * Ne + c;
        if (c + 3 < Ne) {
            float4 o;
            o.x = celu01(acc[i][0] + bc[0]);
            o.y = celu01(acc[i][1] + bc[1]);
            o.z = celu01(acc[i][2] + bc[2]);
            o.w = celu01(acc[i][3] + bc[3]);
            *(float4*)(Y + yoff) = o;
        } else {
            #pragma unroll
            for (int j = 0; j < 4; ++j)
                if (c + j < Ne) Y[yoff + j] = celu01(acc[i][j] + bc[j]);
        }
    }
}

// ---------------- layer 3 (160 -> 1) + energy accumulation -----------------
__global__ __launch_bounds__(256) void out_kernel(const float* __restrict__ H2,
                                                  const float* __restrict__ W3,
                                                  const float* __restrict__ b3,
                                                  const int* __restrict__ rowmap,
                                                  const int* __restrict__ bases,
                                                  const int* __restrict__ species,
                                                  float* __restrict__ energy) {
    int row = blockIdx.x;
    if (row >= bases[7]) return;
    int atom = rowmap[row];
    if (atom < 0) return;
    int s = species[atom];
    int e = threadIdx.x >> 5, lane = threadIdx.x & 31;
    const float* h = H2 + (size_t)row * 1280 + e * 160;
    const float* w = W3 + (size_t)(e * NSPEC + s) * 160;
    float p = 0.f;
    #pragma unroll
    for (int m = 0; m < 5; ++m)
        p += h[lane + 32 * m] * w[lane + 32 * m];
    #pragma unroll
    for (int off = 16; off > 0; off >>= 1)
        p += __shfl_down(p, off, 32);
    if (lane == 0)
        atomicAdd(&energy[atom >> 5], (p + b3[e * NSPEC + s]) * 0.125f);
}

extern "C" void kernel_launch(void* const* d_in, const int* in_sizes, int n_in,
                              void* d_out, int out_size, void* d_ws, size_t ws_size,
                              hipStream_t stream) {
    (void)in_sizes; (void)n_in; (void)out_size; (void)ws_size;
    const int* species = (const int*)d_in[0];
    const float* coords = (const float*)d_in[1];
    const float* W0 = (const float*)d_in[2];
    const float* b0 = (const float*)d_in[3];
    const float* W1 = (const float*)d_in[4];
    const float* b1 = (const float*)d_in[5];
    const float* W2 = (const float*)d_in[6];
    const float* b2 = (const float*)d_in[7];
    const float* W3 = (const float*)d_in[8];
    const float* b3 = (const float*)d_in[9];
    const float* sae = (const float*)d_in[10];
    float* energy = (float*)d_out;

    char* w = (char*)d_ws;
    float* aev = (float*)w;                     w += (size_t)NATOM * DIN * 4;       // 8.26 MB
    float* H0  = (float*)w;                     w += (size_t)MAXROWS * 2048 * 4;    // 20.45 MB
    float* H1  = (float*)w;                     w += (size_t)MAXROWS * 1536 * 4;    // 15.34 MB
    float* H2  = (float*)w;                     w += (size_t)MAXROWS * 1280 * 4;    // 12.78 MB
    int* lists  = (int*)w;                      w += (size_t)NSPEC * NATOM * 4;
    int* rowmap = (int*)w;                      w += (size_t)MAXROWS * 4;
    int* counts = (int*)w;                      w += 32;
    int* bases  = (int*)w;

    hipLaunchKernelGGL(init_kernel, dim3(1), dim3(64), 0, stream,
                       species, sae, energy, counts);
    hipLaunchKernelGGL(bucket_kernel, dim3(8), dim3(256), 0, stream,
                       species, counts, lists);
    hipLaunchKernelGGL(prep_kernel, dim3(1), dim3(256), 0, stream,
                       counts, lists, bases, rowmap);
    hipLaunchKernelGGL(aev_kernel, dim3(NATOM), dim3(256), 0, stream,
                       species, coords, aev);
    // L0: gather aev rows via rowmap; [rows,1008] @ W0[es][1008][256] -> H0[rows][2048]
    hipLaunchKernelGGL(gemm_es, dim3(4, 32, 56), dim3(256), 0, stream,
                       aev, DIN, 0, rowmap, W0, b0, H0, 2048, DIN, 256, 63, bases, counts);
    // L1: H0 (xeb=256) @ W1[es][256][192] -> H1[rows][1536]
    hipLaunchKernelGGL(gemm_es, dim3(3, 32, 56), dim3(256), 0, stream,
                       H0, 2048, 256, (const int*)nullptr, W1, b1, H1, 1536, 256, 192, 16, bases, counts);
    // L2: H1 (xeb=192) @ W2[es][192][160] -> H2[rows][1280]
    hipLaunchKernelGGL(gemm_es, dim3(3, 32, 56), dim3(256), 0, stream,
                       H1, 1536, 192, (const int*)nullptr, W2, b2, H2, 1280, 192, 160, 12, bases, counts);
    // L3 + energy
    hipLaunchKernelGGL(out_kernel, dim3(MAXROWS), dim3(256), 0, stream,
                       H2, W3, b3, rowmap, bases, species, energy);
}

// Round 8
// 371.831 us; speedup vs baseline: 5.9936x; 1.6866x over previous
//
#include <hip/hip_runtime.h>
#include <hip/hip_bf16.h>

#define NSPEC 7
#define NATOM 2048
#define DIN 1008
#define KP0 1024
#define MAXROWS 2496

#define PI_F 3.14159265358979323846f

typedef __attribute__((ext_vector_type(8))) short s16x8;
typedef __attribute__((ext_vector_type(16))) float f32x16;

__device__ __forceinline__ short f2bf(float f) {
    unsigned u = __float_as_uint(f);
    unsigned r = (u + 0x7FFFu + ((u >> 16) & 1u)) >> 16;
    return (short)r;
}
__device__ __forceinline__ float bf2f(short s) {
    return __uint_as_float(((unsigned)(unsigned short)s) << 16);
}
__device__ __forceinline__ float celu01(float x) {
    return x > 0.f ? x : 0.1f * expm1f(x * 10.f);
}

// ---------------- init: zero counts, energy[b] = sum_a sae[species] --------
__global__ __launch_bounds__(64) void init_kernel(const int* __restrict__ species,
                                                  const float* __restrict__ sae,
                                                  float* __restrict__ energy,
                                                  int* __restrict__ counts) {
    int t = threadIdx.x;
    if (t < NSPEC) counts[t] = 0;
    float ssum = 0.f;
    for (int j = 0; j < 32; ++j) ssum += sae[species[t * 32 + j]];
    energy[t] = ssum;
}

// ---------------- bucket atoms by species ----------------------------------
__global__ __launch_bounds__(256) void bucket_kernel(const int* __restrict__ species,
                                                     int* __restrict__ counts,
                                                     int* __restrict__ lists) {
    int a = blockIdx.x * 256 + threadIdx.x;
    if (a < NATOM) {
        int s = species[a];
        int p = atomicAdd(&counts[s], 1);
        lists[s * NATOM + p] = a;
    }
}

// ---------------- prefix bases (64-padded) + rowmap ------------------------
__global__ __launch_bounds__(256) void prep_kernel(const int* __restrict__ counts,
                                                   const int* __restrict__ lists,
                                                   int* __restrict__ bases,
                                                   int* __restrict__ rowmap) {
    int t = threadIdx.x;
    int sb = 0;
    for (int s = 0; s < NSPEC; ++s) {
        int n = counts[s];
        int padc = (n + 63) & ~63;
        if (t == 0) bases[s] = sb;
        for (int p = t; p < padc; p += 256)
            rowmap[sb + p] = (p < n) ? lists[s * NATOM + p] : -1;
        sb += padc;
    }
    if (t == 0) bases[7] = sb;
}

// ---------------- weight transpose+convert: Wt[es][n][k] = bf16(W[es][k][n])
__global__ __launch_bounds__(256) void wtrans_kernel(const float* __restrict__ W,
                                                     short* __restrict__ Wt,
                                                     int K, int Kp, int N) {
    int nn = blockIdx.x, es = blockIdx.y;
    const float* src = W + (size_t)es * K * N + nn;
    short* dst = Wt + ((size_t)es * N + nn) * Kp;
    for (int k = threadIdx.x; k < Kp; k += 256)
        dst[k] = (k < K) ? f2bf(src[(size_t)k * N]) : (short)0;
}

// ---------------- AEV: one block per (b,i), bf16 out (ld 1024, zero pad) ---
__global__ __launch_bounds__(256) void aev_kernel(const int* __restrict__ species,
                                                  const float* __restrict__ coords,
                                                  short* __restrict__ aevb) {
    const int bi = blockIdx.x;
    const int b = bi >> 5, i = bi & 31;
    const int tid = threadIdx.x;

    __shared__ float ux[32], uy[32], uz[32], dst[32], fcr[32], fca[32];
    __shared__ int spc[32];
    __shared__ float cs_[496], sn_[496], ad_[496], w_[496];
    __shared__ int bk_[496];
    __shared__ int npairs;
    __shared__ float ang[896];
    __shared__ float rad[112];

    if (tid == 0) npairs = 0;
    for (int x = tid; x < 896; x += 256) ang[x] = 0.f;
    if (tid < 112) rad[tid] = 0.f;
    if (tid < 32) {
        int j = tid;
        float dx = coords[(b * 32 + j) * 3 + 0] - coords[(b * 32 + i) * 3 + 0];
        float dy = coords[(b * 32 + j) * 3 + 1] - coords[(b * 32 + i) * 3 + 1];
        float dz = coords[(b * 32 + j) * 3 + 2] - coords[(b * 32 + i) * 3 + 2];
        float d = sqrtf(dx * dx + dy * dy + dz * dz + 1e-12f);
        float inv = 1.f / d;
        ux[j] = dx * inv; uy[j] = dy * inv; uz[j] = dz * inv;
        dst[j] = d;
        fcr[j] = (j != i && d < 5.1f) ? 0.5f * cosf(PI_F * d / 5.1f) + 0.5f : 0.f;
        fca[j] = (j != i && d < 3.5f) ? 0.5f * cosf(PI_F * d / 3.5f) + 0.5f : 0.f;
        spc[j] = species[b * 32 + j];
    }
    __syncthreads();

    for (int p = tid; p < 496; p += 256) {
        int j = (int)floorf((63.0f - sqrtf(3969.0f - 8.0f * (float)p)) * 0.5f);
        while ((j + 1) * (63 - (j + 1)) / 2 <= p) ++j;
        while (j * (63 - j) / 2 > p) --j;
        int k = p - j * (63 - j) / 2 + j + 1;
        float w = fca[j] * fca[k];
        if (w > 0.f) {
            float ct = ux[j] * ux[k] + uy[j] * uy[k] + uz[j] * uz[k];
            ct = fminf(1.f, fmaxf(-1.f, ct));
            float cs = 0.95f * ct;
            float sn = sqrtf(1.f - cs * cs);
            int idx = atomicAdd(&npairs, 1);
            cs_[idx] = cs;
            sn_[idx] = sn;
            ad_[idx] = 0.5f * (dst[j] + dst[k]);
            w_[idx] = 2.f * w;
            int sj = spc[j], sk = spc[k];
            int lo = min(sj, sk), hi = max(sj, sk);
            bk_[idx] = lo * 7 - lo * (lo - 1) / 2 + (hi - lo);
        }
    }
    if (tid < 16) {
        float shf = 0.8f + 0.26875f * (float)tid;
        for (int j = 0; j < 32; ++j) {
            if (fcr[j] > 0.f) {
                float dd = dst[j] - shf;
                float v = 0.25f * expf(-19.7f * dd * dd) * fcr[j];
                atomicAdd(&rad[spc[j] * 16 + tid], v);
            }
        }
    }
    __syncthreads();

    const float CZ[4] = {0.92387953f, 0.38268343f, -0.38268343f, -0.92387953f};
    const float SZ[4] = {0.38268343f, 0.92387953f, 0.92387953f, 0.38268343f};
    const int np = npairs;
    const int t = tid & 31, z = t >> 3, aa = t & 7;
    const float cz = CZ[z], sz = SZ[z];
    const float shfa = 0.8f + 0.3375f * (float)aa;
    for (int pr = tid >> 5; pr < np; pr += 8) {
        float f1b = 0.5f * (1.f + cs_[pr] * cz + sn_[pr] * sz);
        float f1 = exp2f(14.1f * log2f(fmaxf(f1b, 1e-30f)));
        float d2 = ad_[pr] - shfa;
        float f2 = expf(-12.5f * d2 * d2);
        atomicAdd(&ang[bk_[pr] * 32 + t], w_[pr] * f1 * f2);
    }
    __syncthreads();
    short* out = aevb + (size_t)(b * 32 + i) * KP0;
    for (int x = tid; x < 112; x += 256) out[x] = f2bf(rad[x]);
    for (int x = tid; x < 896; x += 256) out[112 + x] = f2bf(ang[x]);
    if (tid < 16) out[1008 + tid] = 0;
}

// ---------------- bf16 MFMA GEMM: Y = celu(X @ W + b), per (es) ------------
// X bf16 rows (rowgather: aevb[atom], else X[(base+r)*ldx + xeb*e]).
// Wt bf16 [es][Ne][Kp] (col-major per es), bias fp32 [es][Ne].
// Y bf16 [(base+r)*ldy + e*Ne + c]. Block 256 = 4 waves (2x2), tile 64x64,
// K-step 64, v_mfma_f32_32x32x16_bf16, single-buffer LDS + reg prefetch.
__global__ __launch_bounds__(256) void gemm_mfma(
    const short* __restrict__ X, int ldx, int xeb,
    const int* __restrict__ rowgather,
    const short* __restrict__ Wt,
    const float* __restrict__ Bv,
    short* __restrict__ Y, int ldy,
    int Kp, int Ne, int NT,
    const int* __restrict__ bases, const int* __restrict__ counts) {

    const int es = blockIdx.z;
    const int e = es / NSPEC, s = es % NSPEC;
    const int n = counts[s];
    const int rows0 = blockIdx.y * 64;
    if (rows0 >= n) return;
    const int base = bases[s];
    const int col0 = blockIdx.x * 64;

    const int tid = threadIdx.x;
    const int lane = tid & 63, wave = tid >> 6;
    const int wr = wave >> 1, wc = wave & 1;
    const int l31 = lane & 31, lh = lane >> 5;

    __shared__ short Xt[64][72];   // [row][k], stride 144B -> b128 aligned
    __shared__ short Wts[64][72];  // [col][k]

    const int sr = tid >> 2, sk = (tid & 3) * 16;

    const short* Xrow;
    bool xv = true;
    if (rowgather) {
        int atom = rowgather[base + rows0 + sr];
        xv = atom >= 0;
        Xrow = X + (size_t)(xv ? atom : 0) * ldx;
    } else {
        Xrow = X + (size_t)(base + rows0 + sr) * ldx + (size_t)xeb * e;
    }
    const short* Wrow = Wt + ((size_t)es * Ne + min(col0 + sr, Ne - 1)) * (size_t)Kp;

    f32x16 acc;
    #pragma unroll
    for (int r = 0; r < 16; ++r) acc[r] = 0.f;

    const uint4 zz = make_uint4(0u, 0u, 0u, 0u);
    uint4 xl0, xl1, wl0, wl1;
    xl0 = xv ? *(const uint4*)(Xrow + sk) : zz;
    xl1 = xv ? *(const uint4*)(Xrow + sk + 8) : zz;
    wl0 = *(const uint4*)(Wrow + sk);
    wl1 = *(const uint4*)(Wrow + sk + 8);

    for (int t = 0; t < NT; ++t) {
        if (t > 0) __syncthreads();
        *(uint4*)&Xt[sr][sk]      = xl0;
        *(uint4*)&Xt[sr][sk + 8]  = xl1;
        *(uint4*)&Wts[sr][sk]     = wl0;
        *(uint4*)&Wts[sr][sk + 8] = wl1;
        __syncthreads();
        if (t + 1 < NT) {
            const int k0 = (t + 1) * 64;
            xl0 = xv ? *(const uint4*)(Xrow + k0 + sk) : zz;
            xl1 = xv ? *(const uint4*)(Xrow + k0 + sk + 8) : zz;
            wl0 = *(const uint4*)(Wrow + k0 + sk);
            wl1 = *(const uint4*)(Wrow + k0 + sk + 8);
        }
        #pragma unroll
        for (int kk = 0; kk < 4; ++kk) {
            s16x8 a = *(const s16x8*)&Xt[wr * 32 + l31][kk * 16 + lh * 8];
            s16x8 b = *(const s16x8*)&Wts[wc * 32 + l31][kk * 16 + lh * 8];
            acc = __builtin_amdgcn_mfma_f32_32x32x16_bf16(a, b, acc, 0, 0, 0);
        }
    }

    const int ccol = col0 + wc * 32 + l31;
    if (ccol < Ne) {
        const float bias = Bv[(size_t)es * Ne + ccol];
        const int rbase = base + rows0 + wr * 32 + 4 * lh;
        #pragma unroll
        for (int r = 0; r < 16; ++r) {
            int row = rbase + (r & 3) + 8 * (r >> 2);
            float v = celu01(acc[r] + bias);
            Y[(size_t)row * ldy + (size_t)e * Ne + ccol] = f2bf(v);
        }
    }
}

// ---------------- layer 3 (160 -> 1) + energy accumulation -----------------
__global__ __launch_bounds__(256) void out_kernel(const short* __restrict__ H2,
                                                  const float* __restrict__ W3,
                                                  const float* __restrict__ b3,
                                                  const int* __restrict__ rowmap,
                                                  const int* __restrict__ bases,
                                                  const int* __restrict__ species,
                                                  float* __restrict__ energy) {
    int row = blockIdx.x;
    if (row >= bases[7]) return;
    int atom = rowmap[row];
    if (atom < 0) return;
    int s = species[atom];
    int e = threadIdx.x >> 5, lane = threadIdx.x & 31;
    const short* h = H2 + (size_t)row * 1280 + e * 160;
    const float* w = W3 + (size_t)(e * NSPEC + s) * 160;
    float p = 0.f;
    #pragma unroll
    for (int m = 0; m < 5; ++m)
        p += bf2f(h[lane + 32 * m]) * w[lane + 32 * m];
    #pragma unroll
    for (int off = 16; off > 0; off >>= 1)
        p += __shfl_down(p, off, 32);
    if (lane == 0)
        atomicAdd(&energy[atom >> 5], (p + b3[e * NSPEC + s]) * 0.125f);
}

extern "C" void kernel_launch(void* const* d_in, const int* in_sizes, int n_in,
                              void* d_out, int out_size, void* d_ws, size_t ws_size,
                              hipStream_t stream) {
    (void)in_sizes; (void)n_in; (void)out_size; (void)ws_size;
    const int* species = (const int*)d_in[0];
    const float* coords = (const float*)d_in[1];
    const float* W0 = (const float*)d_in[2];
    const float* b0 = (const float*)d_in[3];
    const float* W1 = (const float*)d_in[4];
    const float* b1 = (const float*)d_in[5];
    const float* W2 = (const float*)d_in[6];
    const float* b2 = (const float*)d_in[7];
    const float* W3 = (const float*)d_in[8];
    const float* b3 = (const float*)d_in[9];
    const float* sae = (const float*)d_in[10];
    float* energy = (float*)d_out;

    char* w = (char*)d_ws;
    short* Wbuf = (short*)w;   w += (size_t)56 * 256 * KP0 * 2;   // 29.36 MB (W0t)
    short* H0   = (short*)w;   w += (size_t)MAXROWS * 2048 * 2;   // 10.22 MB
    short* H1   = (short*)w;   w += (size_t)MAXROWS * 1536 * 2;   //  7.67 MB
    short* aevb = (short*)w;   w += (size_t)NATOM * KP0 * 2;      //  4.19 MB
    int* lists  = (int*)w;     w += (size_t)NSPEC * NATOM * 4;
    int* rowmap = (int*)w;     w += MAXROWS * 4;
    int* counts = (int*)w;     w += 32;
    int* bases  = (int*)w;
    // after L0 completes, Wbuf region is reused (stream-ordered):
    short* W1t = Wbuf;                                  // 5.50 MB
    short* W2t = Wbuf + (size_t)56 * 192 * 256;         // 3.44 MB
    short* H2  = W2t + (size_t)56 * 160 * 192;          // 6.39 MB

    hipLaunchKernelGGL(init_kernel, dim3(1), dim3(64), 0, stream,
                       species, sae, energy, counts);
    hipLaunchKernelGGL(bucket_kernel, dim3(8), dim3(256), 0, stream,
                       species, counts, lists);
    hipLaunchKernelGGL(prep_kernel, dim3(1), dim3(256), 0, stream,
                       counts, lists, bases, rowmap);
    hipLaunchKernelGGL(wtrans_kernel, dim3(256, 56), dim3(256), 0, stream,
                       W0, Wbuf, DIN, KP0, 256);
    hipLaunchKernelGGL(aev_kernel, dim3(NATOM), dim3(256), 0, stream,
                       species, coords, aevb);
    // L0: aevb (gather) @ W0t -> H0
    hipLaunchKernelGGL(gemm_mfma, dim3(4, 32, 56), dim3(256), 0, stream,
                       aevb, KP0, 0, rowmap, Wbuf, b0, H0, 2048, KP0, 256, 16, bases, counts);
    hipLaunchKernelGGL(wtrans_kernel, dim3(192, 56), dim3(256), 0, stream,
                       W1, W1t, 256, 256, 192);
    hipLaunchKernelGGL(wtrans_kernel, dim3(160, 56), dim3(256), 0, stream,
                       W2, W2t, 192, 192, 160);
    // L1: H0 @ W1t -> H1
    hipLaunchKernelGGL(gemm_mfma, dim3(3, 32, 56), dim3(256), 0, stream,
                       H0, 2048, 256, (const int*)nullptr, W1t, b1, H1, 1536, 256, 192, 4, bases, counts);
    // L2: H1 @ W2t -> H2
    hipLaunchKernelGGL(gemm_mfma, dim3(3, 32, 56), dim3(256), 0, stream,
                       H1, 1536, 192, (const int*)nullptr, W2t, b2, H2, 1280, 192, 160, 3, bases, counts);
    // L3 + energy
    hipLaunchKernelGGL(out_kernel, dim3(MAXROWS), dim3(256), 0, stream,
                       H2, W3, b3, rowmap, bases, species, energy);
}

// Round 11
// 284.390 us; speedup vs baseline: 7.8365x; 1.3075x over previous
//
#include <hip/hip_runtime.h>
#include <hip/hip_bf16.h>

#define NSPEC 7
#define NATOM 2048
#define DIN 1008
#define KP0 1024
#define MAXROWS 2496

#define PI_F 3.14159265358979323846f

typedef __attribute__((ext_vector_type(8))) short s16x8;
typedef __attribute__((ext_vector_type(16))) float f32x16;

__device__ __forceinline__ short f2bf(float f) {
    unsigned u = __float_as_uint(f);
    unsigned r = (u + 0x7FFFu + ((u >> 16) & 1u)) >> 16;
    return (short)r;
}
__device__ __forceinline__ float bf2f(short s) {
    return __uint_as_float(((unsigned)(unsigned short)s) << 16);
}
__device__ __forceinline__ float celu01(float x) {
    return x > 0.f ? x : 0.1f * expm1f(x * 10.f);
}

// ---------------- setup: counts, bases, rowmap, energy init (1 block) ------
__global__ __launch_bounds__(256) void setup_kernel(const int* __restrict__ species,
                                                    const float* __restrict__ sae,
                                                    float* __restrict__ energy,
                                                    int* __restrict__ counts,
                                                    int* __restrict__ bases,
                                                    int* __restrict__ rowmap) {
    __shared__ int cnt[8];
    __shared__ int bs[8];
    __shared__ int loc[NATOM];
    const int tid = threadIdx.x;
    if (tid < 8) cnt[tid] = 0;
    __syncthreads();
    for (int a = tid; a < NATOM; a += 256)
        loc[a] = atomicAdd(&cnt[species[a]], 1);
    __syncthreads();
    if (tid == 0) {
        int sb = 0;
        for (int s = 0; s < NSPEC; ++s) { bs[s] = sb; sb += (cnt[s] + 63) & ~63; }
        bs[7] = sb;
    }
    __syncthreads();
    if (tid < 8) bases[tid] = bs[tid];
    if (tid < NSPEC) counts[tid] = cnt[tid];
    for (int r = tid; r < MAXROWS; r += 256) rowmap[r] = -1;
    __syncthreads();
    for (int a = tid; a < NATOM; a += 256)
        rowmap[bs[species[a]] + loc[a]] = a;
    if (tid < 64) {
        float ssum = 0.f;
        for (int j = 0; j < 32; ++j) ssum += sae[species[tid * 32 + j]];
        energy[tid] = ssum;
    }
}

// ---------------- tiled transpose+convert: Wt[es][n][k] = bf16(W[es][k][n]) -
// grid: (Kp/64, ceil(N/64), ES), block 256. Coalesced read + coalesced write.
__global__ __launch_bounds__(256) void wtrans_kernel(const float* __restrict__ W,
                                                     short* __restrict__ Wt,
                                                     int K, int Kp, int N) {
    const int k0 = blockIdx.x * 64, n0 = blockIdx.y * 64, es = blockIdx.z;
    const int tid = threadIdx.x;
    __shared__ short lds[64][66];
    const int r = tid >> 4, c4 = (tid & 15) * 4;

    const float* src = W + (size_t)es * K * N;
    const bool nvalid = (n0 + c4 + 3) < N;
    #pragma unroll
    for (int rr = 0; rr < 64; rr += 16) {
        const int k = k0 + rr + r;
        float4 v = make_float4(0.f, 0.f, 0.f, 0.f);
        if (k < K && nvalid) v = *(const float4*)(src + (size_t)k * N + n0 + c4);
        lds[rr + r][c4 + 0] = f2bf(v.x);
        lds[rr + r][c4 + 1] = f2bf(v.y);
        lds[rr + r][c4 + 2] = f2bf(v.z);
        lds[rr + r][c4 + 3] = f2bf(v.w);
    }
    __syncthreads();
    short* dst = Wt + ((size_t)es * N + n0) * Kp + k0;
    #pragma unroll
    for (int nr = 0; nr < 64; nr += 16) {
        const int n = nr + r;
        if (n0 + n < N) {
            short4 o;
            o.x = lds[c4 + 0][n];
            o.y = lds[c4 + 1][n];
            o.z = lds[c4 + 2][n];
            o.w = lds[c4 + 3][n];
            *(short4*)(dst + (size_t)n * Kp + c4) = o;
        }
    }
}

// ---------------- AEV: one block per (b,i), bf16 out (ld 1024, zero pad) ---
__global__ __launch_bounds__(256) void aev_kernel(const int* __restrict__ species,
                                                  const float* __restrict__ coords,
                                                  short* __restrict__ aevb) {
    const int bi = blockIdx.x;
    const int b = bi >> 5, i = bi & 31;
    const int tid = threadIdx.x;

    __shared__ float ux[32], uy[32], uz[32], dst[32], fcr[32], fca[32];
    __shared__ int spc[32];
    __shared__ float cs_[496], sn_[496], ad_[496], w_[496];
    __shared__ int bk_[496];
    __shared__ int npairs;
    __shared__ float ang[896];
    __shared__ float rad[112];

    if (tid == 0) npairs = 0;
    for (int x = tid; x < 896; x += 256) ang[x] = 0.f;
    if (tid < 112) rad[tid] = 0.f;
    if (tid < 32) {
        int j = tid;
        float dx = coords[(b * 32 + j) * 3 + 0] - coords[(b * 32 + i) * 3 + 0];
        float dy = coords[(b * 32 + j) * 3 + 1] - coords[(b * 32 + i) * 3 + 1];
        float dz = coords[(b * 32 + j) * 3 + 2] - coords[(b * 32 + i) * 3 + 2];
        float d = sqrtf(dx * dx + dy * dy + dz * dz + 1e-12f);
        float inv = 1.f / d;
        ux[j] = dx * inv; uy[j] = dy * inv; uz[j] = dz * inv;
        dst[j] = d;
        fcr[j] = (j != i && d < 5.1f) ? 0.5f * cosf(PI_F * d / 5.1f) + 0.5f : 0.f;
        fca[j] = (j != i && d < 3.5f) ? 0.5f * cosf(PI_F * d / 3.5f) + 0.5f : 0.f;
        spc[j] = species[b * 32 + j];
    }
    __syncthreads();

    for (int p = tid; p < 496; p += 256) {
        int j = (int)floorf((63.0f - sqrtf(3969.0f - 8.0f * (float)p)) * 0.5f);
        while ((j + 1) * (63 - (j + 1)) / 2 <= p) ++j;
        while (j * (63 - j) / 2 > p) --j;
        int k = p - j * (63 - j) / 2 + j + 1;
        float w = fca[j] * fca[k];
        if (w > 0.f) {
            float ct = ux[j] * ux[k] + uy[j] * uy[k] + uz[j] * uz[k];
            ct = fminf(1.f, fmaxf(-1.f, ct));
            float cs = 0.95f * ct;
            float sn = sqrtf(1.f - cs * cs);
            int idx = atomicAdd(&npairs, 1);
            cs_[idx] = cs;
            sn_[idx] = sn;
            ad_[idx] = 0.5f * (dst[j] + dst[k]);
            w_[idx] = 2.f * w;
            int sj = spc[j], sk = spc[k];
            int lo = min(sj, sk), hi = max(sj, sk);
            bk_[idx] = lo * 7 - lo * (lo - 1) / 2 + (hi - lo);
        }
    }
    if (tid < 16) {
        float shf = 0.8f + 0.26875f * (float)tid;
        for (int j = 0; j < 32; ++j) {
            if (fcr[j] > 0.f) {
                float dd = dst[j] - shf;
                float v = 0.25f * expf(-19.7f * dd * dd) * fcr[j];
                atomicAdd(&rad[spc[j] * 16 + tid], v);
            }
        }
    }
    __syncthreads();

    const float CZ[4] = {0.92387953f, 0.38268343f, -0.38268343f, -0.92387953f};
    const float SZ[4] = {0.38268343f, 0.92387953f, 0.92387953f, 0.38268343f};
    const int np = npairs;
    const int t = tid & 31, z = t >> 3, aa = t & 7;
    const float cz = CZ[z], sz = SZ[z];
    const float shfa = 0.8f + 0.3375f * (float)aa;
    for (int pr = tid >> 5; pr < np; pr += 8) {
        float f1b = 0.5f * (1.f + cs_[pr] * cz + sn_[pr] * sz);
        float f1 = exp2f(14.1f * log2f(fmaxf(f1b, 1e-30f)));
        float d2 = ad_[pr] - shfa;
        float f2 = expf(-12.5f * d2 * d2);
        atomicAdd(&ang[bk_[pr] * 32 + t], w_[pr] * f1 * f2);
    }
    __syncthreads();
    short* out = aevb + (size_t)(b * 32 + i) * KP0;
    for (int x = tid; x < 112; x += 256) out[x] = f2bf(rad[x]);
    for (int x = tid; x < 896; x += 256) out[112 + x] = f2bf(ang[x]);
    if (tid < 16) out[1008 + tid] = 0;
}

// ---------------- bf16 MFMA GEMM: Y = celu(X @ W + b), per (es) ------------
__global__ __launch_bounds__(256) void gemm_mfma(
    const short* __restrict__ X, int ldx, int xeb,
    const int* __restrict__ rowgather,
    const short* __restrict__ Wt,
    const float* __restrict__ Bv,
    short* __restrict__ Y, int ldy,
    int Kp, int Ne, int NT,
    const int* __restrict__ bases, const int* __restrict__ counts) {

    const int es = blockIdx.z;
    const int e = es / NSPEC, s = es % NSPEC;
    const int n = counts[s];
    const int rows0 = blockIdx.y * 64;
    if (rows0 >= n) return;
    const int base = bases[s];
    const int col0 = blockIdx.x * 64;

    const int tid = threadIdx.x;
    const int lane = tid & 63, wave = tid >> 6;
    const int wr = wave >> 1, wc = wave & 1;
    const int l31 = lane & 31, lh = lane >> 5;

    __shared__ short Xt[64][72];   // [row][k], stride 144B -> b128 aligned
    __shared__ short Wts[64][72];  // [col][k]

    const int sr = tid >> 2, sk = (tid & 3) * 16;

    const short* Xrow;
    bool xv = true;
    if (rowgather) {
        int atom = rowgather[base + rows0 + sr];
        xv = atom >= 0;
        Xrow = X + (size_t)(xv ? atom : 0) * ldx;
    } else {
        Xrow = X + (size_t)(base + rows0 + sr) * ldx + (size_t)xeb * e;
    }
    const short* Wrow = Wt + ((size_t)es * Ne + min(col0 + sr, Ne - 1)) * (size_t)Kp;

    f32x16 acc;
    #pragma unroll
    for (int r = 0; r < 16; ++r) acc[r] = 0.f;

    const uint4 zz = make_uint4(0u, 0u, 0u, 0u);
    uint4 xl0, xl1, wl0, wl1;
    xl0 = xv ? *(const uint4*)(Xrow + sk) : zz;
    xl1 = xv ? *(const uint4*)(Xrow + sk + 8) : zz;
    wl0 = *(const uint4*)(Wrow + sk);
    wl1 = *(const uint4*)(Wrow + sk + 8);

    for (int t = 0; t < NT; ++t) {
        if (t > 0) __syncthreads();
        *(uint4*)&Xt[sr][sk]      = xl0;
        *(uint4*)&Xt[sr][sk + 8]  = xl1;
        *(uint4*)&Wts[sr][sk]     = wl0;
        *(uint4*)&Wts[sr][sk + 8] = wl1;
        __syncthreads();
        if (t + 1 < NT) {
            const int k0 = (t + 1) * 64;
            xl0 = xv ? *(const uint4*)(Xrow + k0 + sk) : zz;
            xl1 = xv ? *(const uint4*)(Xrow + k0 + sk + 8) : zz;
            wl0 = *(const uint4*)(Wrow + k0 + sk);
            wl1 = *(const uint4*)(Wrow + k0 + sk + 8);
        }
        #pragma unroll
        for (int kk = 0; kk < 4; ++kk) {
            s16x8 a = *(const s16x8*)&Xt[wr * 32 + l31][kk * 16 + lh * 8];
            s16x8 b = *(const s16x8*)&Wts[wc * 32 + l31][kk * 16 + lh * 8];
            acc = __builtin_amdgcn_mfma_f32_32x32x16_bf16(a, b, acc, 0, 0, 0);
        }
    }

    const int ccol = col0 + wc * 32 + l31;
    if (ccol < Ne) {
        const float bias = Bv[(size_t)es * Ne + ccol];
        const int rbase = base + rows0 + wr * 32 + 4 * lh;
        #pragma unroll
        for (int r = 0; r < 16; ++r) {
            int row = rbase + (r & 3) + 8 * (r >> 2);
            float v = celu01(acc[r] + bias);
            Y[(size_t)row * ldy + (size_t)e * Ne + ccol] = f2bf(v);
        }
    }
}

// ---------------- layer 3 (160 -> 1) + energy accumulation -----------------
__global__ __launch_bounds__(256) void out_kernel(const short* __restrict__ H2,
                                                  const float* __restrict__ W3,
                                                  const float* __restrict__ b3,
                                                  const int* __restrict__ rowmap,
                                                  const int* __restrict__ bases,
                                                  const int* __restrict__ species,
                                                  float* __restrict__ energy) {
    int row = blockIdx.x;
    if (row >= bases[7]) return;
    int atom = rowmap[row];
    if (atom < 0) return;
    int s = species[atom];
    int e = threadIdx.x >> 5, lane = threadIdx.x & 31;
    const short* h = H2 + (size_t)row * 1280 + e * 160;
    const float* w = W3 + (size_t)(e * NSPEC + s) * 160;
    float p = 0.f;
    #pragma unroll
    for (int m = 0; m < 5; ++m)
        p += bf2f(h[lane + 32 * m]) * w[lane + 32 * m];
    #pragma unroll
    for (int off = 16; off > 0; off >>= 1)
        p += __shfl_down(p, off, 32);
    if (lane == 0)
        atomicAdd(&energy[atom >> 5], (p + b3[e * NSPEC + s]) * 0.125f);
}

extern "C" void kernel_launch(void* const* d_in, const int* in_sizes, int n_in,
                              void* d_out, int out_size, void* d_ws, size_t ws_size,
                              hipStream_t stream) {
    (void)in_sizes; (void)n_in; (void)out_size; (void)ws_size;
    const int* species = (const int*)d_in[0];
    const float* coords = (const float*)d_in[1];
    const float* W0 = (const float*)d_in[2];
    const float* b0 = (const float*)d_in[3];
    const float* W1 = (const float*)d_in[4];
    const float* b1 = (const float*)d_in[5];
    const float* W2 = (const float*)d_in[6];
    const float* b2 = (const float*)d_in[7];
    const float* W3 = (const float*)d_in[8];
    const float* b3 = (const float*)d_in[9];
    const float* sae = (const float*)d_in[10];
    float* energy = (float*)d_out;

    char* w = (char*)d_ws;
    short* Wbuf = (short*)w;   w += (size_t)56 * 256 * KP0 * 2;   // 29.36 MB (W0t)
    short* H0   = (short*)w;   w += (size_t)MAXROWS * 2048 * 2;   // 10.22 MB
    short* H1   = (short*)w;   w += (size_t)MAXROWS * 1536 * 2;   //  7.67 MB
    short* aevb = (short*)w;   w += (size_t)NATOM * KP0 * 2;      //  4.19 MB
    int* rowmap = (int*)w;     w += MAXROWS * 4;
    int* counts = (int*)w;     w += 32;
    int* bases  = (int*)w;     w += 32;
    // after L0 completes, Wbuf region is reused (stream-ordered):
    short* W1t = Wbuf;                                  // 5.50 MB
    short* W2t = Wbuf + (size_t)56 * 192 * 256;         // 3.44 MB
    short* H2  = W2t + (size_t)56 * 160 * 192;          // 6.39 MB

    hipLaunchKernelGGL(setup_kernel, dim3(1), dim3(256), 0, stream,
                       species, sae, energy, counts, bases, rowmap);
    hipLaunchKernelGGL(wtrans_kernel, dim3(16, 4, 56), dim3(256), 0, stream,
                       W0, Wbuf, DIN, KP0, 256);
    hipLaunchKernelGGL(aev_kernel, dim3(NATOM), dim3(256), 0, stream,
                       species, coords, aevb);
    // L0: aevb (gather) @ W0t -> H0
    hipLaunchKernelGGL(gemm_mfma, dim3(4, 32, 56), dim3(256), 0, stream,
                       aevb, KP0, 0, rowmap, Wbuf, b0, H0, 2048, KP0, 256, 16, bases, counts);
    hipLaunchKernelGGL(wtrans_kernel, dim3(4, 3, 56), dim3(256), 0, stream,
                       W1, W1t, 256, 256, 192);
    hipLaunchKernelGGL(wtrans_kernel, dim3(3, 3, 56), dim3(256), 0, stream,
                       W2, W2t, 192, 192, 160);
    // L1: H0 @ W1t -> H1
    hipLaunchKernelGGL(gemm_mfma, dim3(3, 32, 56), dim3(256), 0, stream,
                       H0, 2048, 256, (const int*)nullptr, W1t, b1, H1, 1536, 256, 192, 4, bases, counts);
    // L2: H1 @ W2t -> H2
    hipLaunchKernelGGL(gemm_mfma, dim3(3, 32, 56), dim3(256), 0, stream,
                       H1, 1536, 192, (const int*)nullptr, W2t, b2, H2, 1280, 192, 160, 3, bases, counts);
    // L3 + energy
    hipLaunchKernelGGL(out_kernel, dim3(MAXROWS), dim3(256), 0, stream,
                       H2, W3, b3, rowmap, bases, species, energy);
}

// Round 12
// 240.688 us; speedup vs baseline: 9.2594x; 1.1816x over previous
//
#include <hip/hip_runtime.h>
#include <hip/hip_bf16.h>

#define NSPEC 7
#define NATOM 2048
#define DIN 1008
#define KP0 1024
#define MAXROWS 2496

#define PI_F 3.14159265358979323846f

typedef __attribute__((ext_vector_type(8))) short s16x8;
typedef __attribute__((ext_vector_type(16))) float f32x16;

__device__ __forceinline__ short f2bf(float f) {
    unsigned u = __float_as_uint(f);
    unsigned r = (u + 0x7FFFu + ((u >> 16) & 1u)) >> 16;
    return (short)r;
}
__device__ __forceinline__ float bf2f(short s) {
    return __uint_as_float(((unsigned)(unsigned short)s) << 16);
}
__device__ __forceinline__ float celu01(float x) {
    return x > 0.f ? x : 0.1f * expm1f(x * 10.f);
}

// ---------------- setup: counts, bases, rowmap, energy init (1 block) ------
__global__ __launch_bounds__(256) void setup_kernel(const int* __restrict__ species,
                                                    const float* __restrict__ sae,
                                                    float* __restrict__ energy,
                                                    int* __restrict__ counts,
                                                    int* __restrict__ bases,
                                                    int* __restrict__ rowmap) {
    __shared__ int cnt[8];
    __shared__ int bs[8];
    __shared__ int loc[NATOM];
    const int tid = threadIdx.x;
    if (tid < 8) cnt[tid] = 0;
    __syncthreads();
    for (int a = tid; a < NATOM; a += 256)
        loc[a] = atomicAdd(&cnt[species[a]], 1);
    __syncthreads();
    if (tid == 0) {
        int sb = 0;
        for (int s = 0; s < NSPEC; ++s) { bs[s] = sb; sb += (cnt[s] + 63) & ~63; }
        bs[7] = sb;
    }
    __syncthreads();
    if (tid < 8) bases[tid] = bs[tid];
    if (tid < NSPEC) counts[tid] = cnt[tid];
    for (int r = tid; r < MAXROWS; r += 256) rowmap[r] = -1;
    __syncthreads();
    for (int a = tid; a < NATOM; a += 256)
        rowmap[bs[species[a]] + loc[a]] = a;
    if (tid < 64) {
        float ssum = 0.f;
        for (int j = 0; j < 32; ++j) ssum += sae[species[tid * 32 + j]];
        energy[tid] = ssum;
    }
}

// ---------------- tiled transpose+convert: Wt[es][n][k] = bf16(W[es][k][n]) -
__global__ __launch_bounds__(256) void wtrans_kernel(const float* __restrict__ W,
                                                     short* __restrict__ Wt,
                                                     int K, int Kp, int N) {
    const int k0 = blockIdx.x * 64, n0 = blockIdx.y * 64, es = blockIdx.z;
    const int tid = threadIdx.x;
    __shared__ short lds[64][66];
    const int r = tid >> 4, c4 = (tid & 15) * 4;

    const float* src = W + (size_t)es * K * N;
    const bool nvalid = (n0 + c4 + 3) < N;
    #pragma unroll
    for (int rr = 0; rr < 64; rr += 16) {
        const int k = k0 + rr + r;
        float4 v = make_float4(0.f, 0.f, 0.f, 0.f);
        if (k < K && nvalid) v = *(const float4*)(src + (size_t)k * N + n0 + c4);
        lds[rr + r][c4 + 0] = f2bf(v.x);
        lds[rr + r][c4 + 1] = f2bf(v.y);
        lds[rr + r][c4 + 2] = f2bf(v.z);
        lds[rr + r][c4 + 3] = f2bf(v.w);
    }
    __syncthreads();
    short* dst = Wt + ((size_t)es * N + n0) * Kp + k0;
    #pragma unroll
    for (int nr = 0; nr < 64; nr += 16) {
        const int n = nr + r;
        if (n0 + n < N) {
            short4 o;
            o.x = lds[c4 + 0][n];
            o.y = lds[c4 + 1][n];
            o.z = lds[c4 + 2][n];
            o.w = lds[c4 + 3][n];
            *(short4*)(dst + (size_t)n * Kp + c4) = o;
        }
    }
}

// ---------------- AEV: one block per (b,i), bf16 out (ld 1024, zero pad) ---
__global__ __launch_bounds__(256) void aev_kernel(const int* __restrict__ species,
                                                  const float* __restrict__ coords,
                                                  short* __restrict__ aevb) {
    const int bi = blockIdx.x;
    const int b = bi >> 5, i = bi & 31;
    const int tid = threadIdx.x;

    __shared__ float ux[32], uy[32], uz[32], dst[32], fcr[32], fca[32];
    __shared__ int spc[32];
    __shared__ float cs_[496], sn_[496], ad_[496], w_[496];
    __shared__ int bk_[496];
    __shared__ int npairs;
    __shared__ float ang[896];
    __shared__ float rad[112];

    if (tid == 0) npairs = 0;
    for (int x = tid; x < 896; x += 256) ang[x] = 0.f;
    if (tid < 112) rad[tid] = 0.f;
    if (tid < 32) {
        int j = tid;
        float dx = coords[(b * 32 + j) * 3 + 0] - coords[(b * 32 + i) * 3 + 0];
        float dy = coords[(b * 32 + j) * 3 + 1] - coords[(b * 32 + i) * 3 + 1];
        float dz = coords[(b * 32 + j) * 3 + 2] - coords[(b * 32 + i) * 3 + 2];
        float d = sqrtf(dx * dx + dy * dy + dz * dz + 1e-12f);
        float inv = 1.f / d;
        ux[j] = dx * inv; uy[j] = dy * inv; uz[j] = dz * inv;
        dst[j] = d;
        fcr[j] = (j != i && d < 5.1f) ? 0.5f * cosf(PI_F * d / 5.1f) + 0.5f : 0.f;
        fca[j] = (j != i && d < 3.5f) ? 0.5f * cosf(PI_F * d / 3.5f) + 0.5f : 0.f;
        spc[j] = species[b * 32 + j];
    }
    __syncthreads();

    for (int p = tid; p < 496; p += 256) {
        int j = (int)floorf((63.0f - sqrtf(3969.0f - 8.0f * (float)p)) * 0.5f);
        while ((j + 1) * (63 - (j + 1)) / 2 <= p) ++j;
        while (j * (63 - j) / 2 > p) --j;
        int k = p - j * (63 - j) / 2 + j + 1;
        float w = fca[j] * fca[k];
        if (w > 0.f) {
            float ct = ux[j] * ux[k] + uy[j] * uy[k] + uz[j] * uz[k];
            ct = fminf(1.f, fmaxf(-1.f, ct));
            float cs = 0.95f * ct;
            float sn = sqrtf(1.f - cs * cs);
            int idx = atomicAdd(&npairs, 1);
            cs_[idx] = cs;
            sn_[idx] = sn;
            ad_[idx] = 0.5f * (dst[j] + dst[k]);
            w_[idx] = 2.f * w;
            int sj = spc[j], sk = spc[k];
            int lo = min(sj, sk), hi = max(sj, sk);
            bk_[idx] = lo * 7 - lo * (lo - 1) / 2 + (hi - lo);
        }
    }
    if (tid < 16) {
        float shf = 0.8f + 0.26875f * (float)tid;
        for (int j = 0; j < 32; ++j) {
            if (fcr[j] > 0.f) {
                float dd = dst[j] - shf;
                float v = 0.25f * expf(-19.7f * dd * dd) * fcr[j];
                atomicAdd(&rad[spc[j] * 16 + tid], v);
            }
        }
    }
    __syncthreads();

    const float CZ[4] = {0.92387953f, 0.38268343f, -0.38268343f, -0.92387953f};
    const float SZ[4] = {0.38268343f, 0.92387953f, 0.92387953f, 0.38268343f};
    const int np = npairs;
    const int t = tid & 31, z = t >> 3, aa = t & 7;
    const float cz = CZ[z], sz = SZ[z];
    const float shfa = 0.8f + 0.3375f * (float)aa;
    for (int pr = tid >> 5; pr < np; pr += 8) {
        float f1b = 0.5f * (1.f + cs_[pr] * cz + sn_[pr] * sz);
        float f1 = exp2f(14.1f * log2f(fmaxf(f1b, 1e-30f)));
        float d2 = ad_[pr] - shfa;
        float f2 = expf(-12.5f * d2 * d2);
        atomicAdd(&ang[bk_[pr] * 32 + t], w_[pr] * f1 * f2);
    }
    __syncthreads();
    short* out = aevb + (size_t)(b * 32 + i) * KP0;
    for (int x = tid; x < 112; x += 256) out[x] = f2bf(rad[x]);
    for (int x = tid; x < 896; x += 256) out[112 + x] = f2bf(ang[x]);
    if (tid < 16) out[1008 + tid] = 0;
}

// ---------------- bf16 MFMA GEMM: Y = celu(X @ W + b), per (es) ------------
__global__ __launch_bounds__(256) void gemm_mfma(
    const short* __restrict__ X, int ldx, int xeb,
    const int* __restrict__ rowgather,
    const short* __restrict__ Wt,
    const float* __restrict__ Bv,
    short* __restrict__ Y, int ldy,
    int Kp, int Ne, int NT,
    const int* __restrict__ bases, const int* __restrict__ counts) {

    const int es = blockIdx.z;
    const int e = es / NSPEC, s = es % NSPEC;
    const int n = counts[s];
    const int rows0 = blockIdx.y * 64;
    if (rows0 >= n) return;
    const int base = bases[s];
    const int col0 = blockIdx.x * 64;

    const int tid = threadIdx.x;
    const int lane = tid & 63, wave = tid >> 6;
    const int wr = wave >> 1, wc = wave & 1;
    const int l31 = lane & 31, lh = lane >> 5;

    __shared__ short Xt[64][72];   // [row][k], stride 144B -> b128 aligned
    __shared__ short Wts[64][72];  // [col][k]

    const int sr = tid >> 2, sk = (tid & 3) * 16;

    const short* Xrow;
    bool xv = true;
    if (rowgather) {
        int atom = rowgather[base + rows0 + sr];
        xv = atom >= 0;
        Xrow = X + (size_t)(xv ? atom : 0) * ldx;
    } else {
        Xrow = X + (size_t)(base + rows0 + sr) * ldx + (size_t)xeb * e;
    }
    const short* Wrow = Wt + ((size_t)es * Ne + min(col0 + sr, Ne - 1)) * (size_t)Kp;

    f32x16 acc;
    #pragma unroll
    for (int r = 0; r < 16; ++r) acc[r] = 0.f;

    const uint4 zz = make_uint4(0u, 0u, 0u, 0u);
    uint4 xl0, xl1, wl0, wl1;
    xl0 = xv ? *(const uint4*)(Xrow + sk) : zz;
    xl1 = xv ? *(const uint4*)(Xrow + sk + 8) : zz;
    wl0 = *(const uint4*)(Wrow + sk);
    wl1 = *(const uint4*)(Wrow + sk + 8);

    for (int t = 0; t < NT; ++t) {
        if (t > 0) __syncthreads();
        *(uint4*)&Xt[sr][sk]      = xl0;
        *(uint4*)&Xt[sr][sk + 8]  = xl1;
        *(uint4*)&Wts[sr][sk]     = wl0;
        *(uint4*)&Wts[sr][sk + 8] = wl1;
        __syncthreads();
        if (t + 1 < NT) {
            const int k0 = (t + 1) * 64;
            xl0 = xv ? *(const uint4*)(Xrow + k0 + sk) : zz;
            xl1 = xv ? *(const uint4*)(Xrow + k0 + sk + 8) : zz;
            wl0 = *(const uint4*)(Wrow + k0 + sk);
            wl1 = *(const uint4*)(Wrow + k0 + sk + 8);
        }
        #pragma unroll
        for (int kk = 0; kk < 4; ++kk) {
            s16x8 a = *(const s16x8*)&Xt[wr * 32 + l31][kk * 16 + lh * 8];
            s16x8 b = *(const s16x8*)&Wts[wc * 32 + l31][kk * 16 + lh * 8];
            acc = __builtin_amdgcn_mfma_f32_32x32x16_bf16(a, b, acc, 0, 0, 0);
        }
    }

    const int ccol = col0 + wc * 32 + l31;
    if (ccol < Ne) {
        const float bias = Bv[(size_t)es * Ne + ccol];
        const int rbase = base + rows0 + wr * 32 + 4 * lh;
        #pragma unroll
        for (int r = 0; r < 16; ++r) {
            int row = rbase + (r & 3) + 8 * (r >> 2);
            float v = celu01(acc[r] + bias);
            Y[(size_t)row * ldy + (size_t)e * Ne + ccol] = f2bf(v);
        }
    }
}

// ---------------- layer 3 (160 -> 1) per row, no global atomics ------------
__global__ __launch_bounds__(256) void out_kernel(const short* __restrict__ H2,
                                                  const float* __restrict__ W3,
                                                  const float* __restrict__ b3,
                                                  const int* __restrict__ rowmap,
                                                  const int* __restrict__ bases,
                                                  const int* __restrict__ species,
                                                  float* __restrict__ rowval) {
    int row = blockIdx.x;
    if (row >= bases[7]) return;
    int atom = rowmap[row];
    if (atom < 0) return;
    int s = species[atom];
    int e = threadIdx.x >> 5, lane = threadIdx.x & 31;
    __shared__ float esum[8];
    const short* h = H2 + (size_t)row * 1280 + e * 160;
    const float* w = W3 + (size_t)(e * NSPEC + s) * 160;
    float p = 0.f;
    #pragma unroll
    for (int m = 0; m < 5; ++m)
        p += bf2f(h[lane + 32 * m]) * w[lane + 32 * m];
    #pragma unroll
    for (int off = 16; off > 0; off >>= 1)
        p += __shfl_down(p, off, 32);
    if (lane == 0) esum[e] = p + b3[e * NSPEC + s];
    __syncthreads();
    if (threadIdx.x == 0) {
        float t = 0.f;
        #pragma unroll
        for (int e2 = 0; e2 < 8; ++e2) t += esum[e2];
        rowval[row] = t * 0.125f;
    }
}

// ---------------- final: rowval -> energy via LDS reduction (1 block) ------
__global__ __launch_bounds__(256) void final_kernel(const float* __restrict__ rowval,
                                                    const int* __restrict__ rowmap,
                                                    const int* __restrict__ bases,
                                                    float* __restrict__ energy) {
    __shared__ float es[64];
    const int tid = threadIdx.x;
    if (tid < 64) es[tid] = 0.f;
    __syncthreads();
    const int nrows = bases[7];
    for (int r = tid; r < nrows; r += 256) {
        int atom = rowmap[r];
        if (atom >= 0) atomicAdd(&es[atom >> 5], rowval[r]);
    }
    __syncthreads();
    if (tid < 64) energy[tid] += es[tid];
}

extern "C" void kernel_launch(void* const* d_in, const int* in_sizes, int n_in,
                              void* d_out, int out_size, void* d_ws, size_t ws_size,
                              hipStream_t stream) {
    (void)in_sizes; (void)n_in; (void)out_size; (void)ws_size;
    const int* species = (const int*)d_in[0];
    const float* coords = (const float*)d_in[1];
    const float* W0 = (const float*)d_in[2];
    const float* b0 = (const float*)d_in[3];
    const float* W1 = (const float*)d_in[4];
    const float* b1 = (const float*)d_in[5];
    const float* W2 = (const float*)d_in[6];
    const float* b2 = (const float*)d_in[7];
    const float* W3 = (const float*)d_in[8];
    const float* b3 = (const float*)d_in[9];
    const float* sae = (const float*)d_in[10];
    float* energy = (float*)d_out;

    char* w = (char*)d_ws;
    short* Wbuf = (short*)w;   w += (size_t)56 * 256 * KP0 * 2;   // 29.36 MB (W0t)
    short* H0   = (short*)w;   w += (size_t)MAXROWS * 2048 * 2;   // 10.22 MB
    short* H1   = (short*)w;   w += (size_t)MAXROWS * 1536 * 2;   //  7.67 MB
    short* aevb = (short*)w;   w += (size_t)NATOM * KP0 * 2;      //  4.19 MB
    float* rowval = (float*)w; w += MAXROWS * 4;
    int* rowmap = (int*)w;     w += MAXROWS * 4;
    int* counts = (int*)w;     w += 32;
    int* bases  = (int*)w;     w += 32;
    // after L0 completes, Wbuf region is reused (stream-ordered):
    short* W1t = Wbuf;                                  // 5.50 MB
    short* W2t = Wbuf + (size_t)56 * 192 * 256;         // 3.44 MB
    short* H2  = W2t + (size_t)56 * 160 * 192;          // 6.39 MB

    hipLaunchKernelGGL(setup_kernel, dim3(1), dim3(256), 0, stream,
                       species, sae, energy, counts, bases, rowmap);
    hipLaunchKernelGGL(wtrans_kernel, dim3(16, 4, 56), dim3(256), 0, stream,
                       W0, Wbuf, DIN, KP0, 256);
    hipLaunchKernelGGL(aev_kernel, dim3(NATOM), dim3(256), 0, stream,
                       species, coords, aevb);
    // L0: aevb (gather) @ W0t -> H0
    hipLaunchKernelGGL(gemm_mfma, dim3(4, 32, 56), dim3(256), 0, stream,
                       aevb, KP0, 0, rowmap, Wbuf, b0, H0, 2048, KP0, 256, 16, bases, counts);
    hipLaunchKernelGGL(wtrans_kernel, dim3(4, 3, 56), dim3(256), 0, stream,
                       W1, W1t, 256, 256, 192);
    hipLaunchKernelGGL(wtrans_kernel, dim3(3, 3, 56), dim3(256), 0, stream,
                       W2, W2t, 192, 192, 160);
    // L1: H0 @ W1t -> H1
    hipLaunchKernelGGL(gemm_mfma, dim3(3, 32, 56), dim3(256), 0, stream,
                       H0, 2048, 256, (const int*)nullptr, W1t, b1, H1, 1536, 256, 192, 4, bases, counts);
    // L2: H1 @ W2t -> H2
    hipLaunchKernelGGL(gemm_mfma, dim3(3, 32, 56), dim3(256), 0, stream,
                       H1, 1536, 192, (const int*)nullptr, W2t, b2, H2, 1280, 192, 160, 3, bases, counts);
    // L3 per-row (no global atomics)
    hipLaunchKernelGGL(out_kernel, dim3(MAXROWS), dim3(256), 0, stream,
                       H2, W3, b3, rowmap, bases, species, rowval);
    // final reduction into energies
    hipLaunchKernelGGL(final_kernel, dim3(1), dim3(256), 0, stream,
                       rowval, rowmap, bases, energy);
}